// Round 12
// baseline (33.870 us; speedup 1.0000x reference)
//
#include <hip/hip_runtime.h>

#define BB 4
#define CC 256
#define HH 50
#define WW 50
#define KK 1000
#define PP 7
#define NBIN 49              // 7*7
#define SCALE 0.0625f        // 1/16
#define CH 64                // channels per gather block
#define NQ (CH / 4)          // 16 channel-quads
#define ROWQ (WW * CC / 4)   // uint4 stride of one y row in pair map = 3200
#define COLQ (CC / 4)        // uint4 stride of one x step = 64
#define WDS 52               // padded Wd rows (ny <= 50)

typedef float    f32x4 __attribute__((ext_vector_type(4)));
typedef _Float16 f16x2 __attribute__((ext_vector_type(2)));

__device__ __forceinline__ f16x2 u2h(unsigned int u) {
    union { unsigned int i; f16x2 h; } c; c.i = u; return c.h;
}
__device__ __forceinline__ unsigned int pack_f16(float lo, float hi) {
    union { f16x2 h; unsigned int i; } c;
    c.h[0] = (_Float16)lo; c.h[1] = (_Float16)hi;   // RNE casts
    return c.i;
}
// d = a.f16[0]*b.f16[0] + a.f16[1]*b.f16[1] + c  (V_DOT2_F32_F16)
__device__ __forceinline__ float dot2h(unsigned int a, unsigned int b, float c) {
#if __has_builtin(__builtin_amdgcn_fdot2)
    return __builtin_amdgcn_fdot2(u2h(a), u2h(b), c, false);
#else
    const f16x2 ah = u2h(a), bh = u2h(b);
    return fmaf((float)ah[0], (float)bh[0], fmaf((float)ah[1], (float)bh[1], c));
#endif
}

// --- per-axis sample computation, replicating reference boundary handling ---
__device__ __forceinline__ void axis_samples(float start, float bin, int p, float limit,
                                             int idx[4], float w[4]) {
#pragma unroll
    for (int i = 0; i < 2; ++i) {
        float s = (float)(p * 2 + i);
        float c = start + bin * (s + 0.5f) * 0.5f;   // /SR==2 exact as *0.5
        bool valid = (c > -1.0f) && (c < limit);
        c = fmaxf(c, 0.0f);
        float low = floorf(c);
        float high;
        if (low >= limit - 1.0f) { low = limit - 1.0f; c = low; high = low; }
        else high = low + 1.0f;
        float frac = c - low;
        idx[i * 2 + 0] = (int)low;
        idx[i * 2 + 1] = (int)high;
        w[i * 2 + 0] = valid ? (1.0f - frac) : 0.0f;
        w[i * 2 + 1] = valid ? frac : 0.0f;
    }
}

// --- NCHW f32 -> pair-interleaved NHWC f16: pair[y][x][c] = (F[x][c], F[x+1][c]) ---
__global__ __launch_bounds__(128) void xpose_kernel(const float* __restrict__ in,
                                                    unsigned int* __restrict__ out) {
    __shared__ float tile[32 * 51];           // stride-51 pad; pad slot = x=50 ghost zero
    const int bid   = blockIdx.x;
    const int e     = bid & 7;                // 32-channel slice
    const int rem   = bid >> 3;
    const int y     = rem % HH;
    const int b     = rem / HH;
    const int t     = threadIdx.x;
    const int cbase = e * 32;
    for (int i = t; i < 32 * 25; i += 128) {
        const int c = i / 25, x2 = i % 25;
        const float2 v = *(const float2*)(in +
            (((size_t)(b * CC + cbase + c) * HH + y) * WW + 2 * x2));
        tile[c * 51 + 2 * x2]     = v.x;
        tile[c * 51 + 2 * x2 + 1] = v.y;
    }
    if (t < 32) tile[t * 51 + 50] = 0.0f;     // x=50 ghost column = 0
    __syncthreads();
    unsigned int* ob = out + ((size_t)(b * HH + y) * WW) * CC + cbase;
    for (int j = t; j < WW * 8; j += 128) {
        const int x  = j >> 3;                // 8 channel-quads per x (this eighth)
        const int c0 = (j & 7) * 4;
        uint4 v;
        v.x = pack_f16(tile[(c0 + 0) * 51 + x], tile[(c0 + 0) * 51 + x + 1]);
        v.y = pack_f16(tile[(c0 + 1) * 51 + x], tile[(c0 + 1) * 51 + x + 1]);
        v.z = pack_f16(tile[(c0 + 2) * 51 + x], tile[(c0 + 2) * 51 + x + 1]);
        v.w = pack_f16(tile[(c0 + 3) * 51 + x], tile[(c0 + 3) * 51 + x + 1]);
        *(uint4*)(ob + (size_t)x * CC + c0) = v;
    }
}

// --- separable gather: block = (ROI, 64-ch quarter); thread = (pw, chq) ---
// out[ph][pw] = sum_y Wd[ph][y] * dot2(pairs, packed f16 x-weights)
__global__ __launch_bounds__(128) void roialign_kernel(const uint4* __restrict__ fmap4,
                                                       const float* __restrict__ rois,
                                                       float* __restrict__ out) {
    __shared__ __align__(16) float sout[CH * NBIN];   // 12544 B, [c][49]
    __shared__ float s_wd[PP][WDS];                   // collapsed y-weights (x0.25)
    __shared__ int          s_xo[PP][2];              // pair base offsets (uint4 units)
    __shared__ unsigned int s_xw[PP][2];              // packed f16 (w_lo, w_hi)

    const int bid     = blockIdx.x;
    const int k       = bid >> 2;        // ROI
    const int quarter = bid & 3;         // channel quarter
    const int t       = threadIdx.x;

    const int   b  = (int)rois[k * 5 + 0];
    const float x1 = rois[k * 5 + 1] * SCALE;
    const float y1 = rois[k * 5 + 2] * SCALE;
    const float x2 = rois[k * 5 + 3] * SCALE;
    const float y2 = rois[k * 5 + 4] * SCALE;
    const float bw = fmaxf(x2 - x1, 1.0f) * (1.0f / PP);
    const float bh = fmaxf(y2 - y1, 1.0f) * (1.0f / PP);

    // y bbox from the monotone extreme samples (s=0 lowest tap, s=13 highest)
    float c0f = fmaxf(y1 + bh * 0.25f, 0.0f);
    float l0 = floorf(c0f);
    if (l0 >= HH - 1.0f) l0 = HH - 1.0f;
    const int ylo = (int)l0;
    float c1f = fmaxf(y1 + bh * 6.75f, 0.0f);
    float l1 = floorf(c1f);
    float h1 = (l1 >= HH - 1.0f) ? (HH - 1.0f) : (l1 + 1.0f);
    const int ny = (int)h1 - ylo + 1;    // <= 50 (indices clamped to [0,49])

    // single-sync table build: thread t<7 owns Wd row t
    if (t < PP) {
        for (int y = 0; y < ny; ++y) s_wd[t][y] = 0.0f;
        int idx[4]; float w[4];
        axis_samples(y1, bh, t, (float)HH, idx, w);
#pragma unroll
        for (int j = 0; j < 4; ++j) s_wd[t][idx[j] - ylo] += 0.25f * w[j];
    } else if (t >= 64 && t < 64 + PP) { // x pair tables (other wave, parallel)
        const int p2 = t - 64;
#pragma unroll
        for (int i = 0; i < 2; ++i) {
            const float s = (float)(p2 * 2 + i);
            float c = x1 + bw * (s + 0.5f) * 0.5f;
            const bool valid = (c > -1.0f) && (c < (float)WW);
            c = fmaxf(c, 0.0f);
            float low = floorf(c);
            float wl, wh;
            if (low >= (float)(WW - 1)) {            // top edge: tap on col 49 only
                low = (float)(WW - 1);
                wl = valid ? 1.0f : 0.0f; wh = 0.0f;
            } else {
                const float fr = c - low;
                wl = valid ? (1.0f - fr) : 0.0f;
                wh = valid ? fr : 0.0f;
            }
            s_xo[p2][i] = (int)low * COLQ;
            s_xw[p2][i] = pack_f16(wl, wh);
        }
    }
    __syncthreads();

    const int pw  = t >> 4;          // 0..6 active, 7 idle
    const int chq = t & 15;
    if (pw < PP) {
        const int xb0 = s_xo[pw][0], xb1 = s_xo[pw][1];
        const unsigned int wp0 = s_xw[pw][0], wp1 = s_xw[pw][1];
        f32x4 acc[PP] = {};
        const uint4* p = fmap4 + (size_t)b * (HH * ROWQ) + (size_t)ylo * ROWQ
                       + quarter * NQ + chq;
#pragma unroll 2
        for (int y = 0; y < ny; ++y, p += ROWQ) {
            const uint4 q0 = p[xb0], q1 = p[xb1];    // 2 loads/row (was 4)
            const float t0 = dot2h(q0.x, wp0, dot2h(q1.x, wp1, 0.0f));
            const float t1 = dot2h(q0.y, wp0, dot2h(q1.y, wp1, 0.0f));
            const float t2 = dot2h(q0.z, wp0, dot2h(q1.z, wp1, 0.0f));
            const float t3 = dot2h(q0.w, wp0, dot2h(q1.w, wp1, 0.0f));
#pragma unroll
            for (int ph = 0; ph < PP; ++ph) {
                const float wy = s_wd[ph][y];        // uniform LDS broadcast
                acc[ph].x = fmaf(wy, t0, acc[ph].x);
                acc[ph].y = fmaf(wy, t1, acc[ph].y);
                acc[ph].z = fmaf(wy, t2, acc[ph].z);
                acc[ph].w = fmaf(wy, t3, acc[ph].w);
            }
        }
        const int c0 = chq * 4;
#pragma unroll
        for (int ph = 0; ph < PP; ++ph) {            // 32 distinct banks x 2 lanes: free
            const int bin = ph * PP + pw;
            sout[(c0 + 0) * NBIN + bin] = acc[ph].x;
            sout[(c0 + 1) * NBIN + bin] = acc[ph].y;
            sout[(c0 + 2) * NBIN + bin] = acc[ph].z;
            sout[(c0 + 3) * NBIN + bin] = acc[ph].w;
        }
    }
    __syncthreads();

    // epilogue: 12544 contiguous bytes per block, nontemporal float4
    f32x4* o4 = (f32x4*)(out + (size_t)k * (CC * NBIN) + (size_t)quarter * (CH * NBIN));
    const f32x4* s4 = (const f32x4*)sout;
    for (int i = t; i < CH * NBIN / 4; i += 128)
        __builtin_nontemporal_store(s4[i], &o4[i]);
}

// --- fallback: direct NCHW f32 (only if ws too small) ---
__global__ __launch_bounds__(256) void roialign_nchw_kernel(const float* __restrict__ fmap,
                                                            const float* __restrict__ rois,
                                                            float* __restrict__ out) {
    __shared__ __align__(16) float sbuf[CC * NBIN];
    const int k = blockIdx.x;
    const int t = threadIdx.x;
    const int   b  = (int)rois[k * 5 + 0];
    const float x1 = rois[k * 5 + 1] * SCALE;
    const float y1 = rois[k * 5 + 2] * SCALE;
    const float x2 = rois[k * 5 + 3] * SCALE;
    const float y2 = rois[k * 5 + 4] * SCALE;
    const float bw = fmaxf(x2 - x1, 1.0f) * (1.0f / PP);
    const float bh = fmaxf(y2 - y1, 1.0f) * (1.0f / PP);
    for (int ph = 0; ph < PP; ++ph) {
        int ys[4]; float wy[4];
        axis_samples(y1, bh, ph, (float)HH, ys, wy);
        for (int pw = 0; pw < PP; ++pw) {
            int xs[4]; float wx[4];
            axis_samples(x1, bw, pw, (float)WW, xs, wx);
            float acc = 0.0f;
#pragma unroll
            for (int i = 0; i < 4; ++i)
#pragma unroll
                for (int j = 0; j < 4; ++j)
                    acc = fmaf(wy[i] * wx[j],
                               fmap[((size_t)(b * CC + t) * HH + ys[i]) * WW + xs[j]], acc);
            sbuf[t * NBIN + ph * PP + pw] = acc * 0.25f;
        }
    }
    __syncthreads();
    float4* o4 = (float4*)(out + (size_t)k * (CC * NBIN));
    const float4* s4 = (const float4*)sbuf;
    for (int i = t; i < (CC * NBIN) / 4; i += 256) o4[i] = s4[i];
}

extern "C" void kernel_launch(void* const* d_in, const int* in_sizes, int n_in,
                              void* d_out, int out_size, void* d_ws, size_t ws_size,
                              hipStream_t stream) {
    const float* input = (const float*)d_in[0];   // [B,C,H,W] f32
    const float* rois  = (const float*)d_in[1];   // [K,5] f32
    float* out = (float*)d_out;                   // [K,C,7,7] f32

    const size_t need = (size_t)BB * HH * WW * CC * sizeof(unsigned int);  // 10.24 MB
    if (ws_size >= need) {
        unsigned int* fmap = (unsigned int*)d_ws;
        xpose_kernel<<<BB * HH * 8, 128, 0, stream>>>(input, fmap);
        roialign_kernel<<<KK * 4, 128, 0, stream>>>((const uint4*)fmap, rois, out);
    } else {
        roialign_nchw_kernel<<<KK, 256, 0, stream>>>(input, rois, out);
    }
}

// Round 13
// 29.136 us; speedup vs baseline: 1.1625x; 1.1625x over previous
//
#include <hip/hip_runtime.h>

#define BB 4
#define CC 256
#define HH 50
#define WW 50
#define KK 1000
#define PP 7
#define NBIN 49              // 7*7
#define SCALE 0.0625f        // 1/16
#define CH 64                // channels per gather block
#define NQ (CH / 4)          // 16 channel-quads
#define ROWQ (WW * CC / 4)   // quad stride of one y row in NHWC = 3200
#define COLQ (CC / 4)        // quad stride of one x step = 64
#define WDS 52               // padded Wd rows (ny <= 50)

typedef float f32x4 __attribute__((ext_vector_type(4)));
typedef float f32x2 __attribute__((ext_vector_type(2)));

__device__ __forceinline__ unsigned short f32_to_bf(float f) {
    union { float f; unsigned int i; } c; c.f = f;
    const unsigned int r = c.i + 0x7FFFu + ((c.i >> 16) & 1u);   // round-nearest-even
    return (unsigned short)(r >> 16);
}
// u = (bf16 a | bf16 b<<16)  ->  {f32(a), f32(b)}
__device__ __forceinline__ f32x2 bfpair(unsigned int u) {
    union { unsigned int i; float f; } a, b;
    a.i = u << 16;
    b.i = u & 0xFFFF0000u;
    f32x2 r; r[0] = a.f; r[1] = b.f;
    return r;
}
// packed fma: compiler emits v_pk_fma_f32 (2 f32/lane/issue)
__device__ __forceinline__ f32x2 fma2(f32x2 a, float b, f32x2 c) {
    return a * b + c;
}

// --- per-axis sample computation, replicating reference boundary handling ---
__device__ __forceinline__ void axis_samples(float start, float bin, int p, float limit,
                                             int idx[4], float w[4]) {
#pragma unroll
    for (int i = 0; i < 2; ++i) {
        float s = (float)(p * 2 + i);
        float c = start + bin * (s + 0.5f) * 0.5f;   // /SR==2 exact as *0.5
        bool valid = (c > -1.0f) && (c < limit);
        c = fmaxf(c, 0.0f);
        float low = floorf(c);
        float high;
        if (low >= limit - 1.0f) { low = limit - 1.0f; c = low; high = low; }
        else high = low + 1.0f;
        float frac = c - low;
        idx[i * 2 + 0] = (int)low;
        idx[i * 2 + 1] = (int)high;
        w[i * 2 + 0] = valid ? (1.0f - frac) : 0.0f;
        w[i * 2 + 1] = valid ? frac : 0.0f;
    }
}

// --- NCHW f32 -> NHWC bf16 transpose: block per (b, y, 32-ch eighth) ---
__global__ __launch_bounds__(128) void xpose_kernel(const float* __restrict__ in,
                                                    unsigned short* __restrict__ out) {
    __shared__ float tile[32 * 51];           // 6528 B, stride-51 pad
    const int bid   = blockIdx.x;
    const int e     = bid & 7;                // 32-channel slice
    const int rem   = bid >> 3;
    const int y     = rem % HH;
    const int b     = rem / HH;
    const int t     = threadIdx.x;
    const int cbase = e * 32;
    for (int i = t; i < 32 * 25; i += 128) {
        const int c = i / 25, x2 = i % 25;
        const float2 v = *(const float2*)(in +
            (((size_t)(b * CC + cbase + c) * HH + y) * WW + 2 * x2));
        tile[c * 51 + 2 * x2]     = v.x;
        tile[c * 51 + 2 * x2 + 1] = v.y;
    }
    __syncthreads();
    unsigned short* ob = out + ((size_t)(b * HH + y) * WW) * CC + cbase;
    for (int j = t; j < WW * 8; j += 128) {
        const int x  = j >> 3;                // 8 channel-quads per x (this eighth)
        const int c0 = (j & 7) * 4;
        ushort4 v;
        v.x = f32_to_bf(tile[(c0 + 0) * 51 + x]);
        v.y = f32_to_bf(tile[(c0 + 1) * 51 + x]);
        v.z = f32_to_bf(tile[(c0 + 2) * 51 + x]);
        v.w = f32_to_bf(tile[(c0 + 3) * 51 + x]);
        *(ushort4*)(ob + (size_t)x * CC + c0) = v;   // keep in L2 for the gather
    }
}

// --- separable gather: block = (ROI, 64-ch quarter); thread = (pw, chq) ---
// out[ph][pw] = sum_y Wd[ph][y] * (sum_j wx[pw][j] * F[y][x_j]), packed-f32 math
__global__ __launch_bounds__(128) void roialign_kernel(const uint2* __restrict__ fmap4,
                                                       const float* __restrict__ rois,
                                                       float* __restrict__ out) {
    __shared__ __align__(16) float sout[CH * NBIN];   // 12544 B, [c][49]
    __shared__ float s_wd[PP][WDS];                   // collapsed y-weights (x0.25)
    __shared__ int   s_xo[PP][4];                     // x tap offsets (quad units)
    __shared__ float s_xw[PP][4];

    const int bid     = blockIdx.x;
    const int k       = bid >> 2;        // ROI
    const int quarter = bid & 3;         // channel quarter (XCD-slice friendly)
    const int t       = threadIdx.x;

    const int   b  = (int)rois[k * 5 + 0];
    const float x1 = rois[k * 5 + 1] * SCALE;
    const float y1 = rois[k * 5 + 2] * SCALE;
    const float x2 = rois[k * 5 + 3] * SCALE;
    const float y2 = rois[k * 5 + 4] * SCALE;
    const float bw = fmaxf(x2 - x1, 1.0f) * (1.0f / PP);
    const float bh = fmaxf(y2 - y1, 1.0f) * (1.0f / PP);

    // y bbox from the monotone extreme samples (s=0 lowest tap, s=13 highest)
    float c0f = fmaxf(y1 + bh * 0.25f, 0.0f);
    float l0 = floorf(c0f);
    if (l0 >= HH - 1.0f) l0 = HH - 1.0f;
    const int ylo = (int)l0;
    float c1f = fmaxf(y1 + bh * 6.75f, 0.0f);
    float l1 = floorf(c1f);
    float h1 = (l1 >= HH - 1.0f) ? (HH - 1.0f) : (l1 + 1.0f);
    const int ny = (int)h1 - ylo + 1;    // <= 50 always (indices clamped to [0,49])

    // single-sync table build: thread t<7 owns Wd row t (zero just [0,ny) + scatter)
    if (t < PP) {
        for (int y = 0; y < ny; ++y) s_wd[t][y] = 0.0f;
        int idx[4]; float w[4];
        axis_samples(y1, bh, t, (float)HH, idx, w);
#pragma unroll
        for (int j = 0; j < 4; ++j) s_wd[t][idx[j] - ylo] += 0.25f * w[j];
    } else if (t >= 64 && t < 64 + PP) {          // x tables (other wave, parallel)
        const int p = t - 64;
        int idx[4]; float w[4];
        axis_samples(x1, bw, p, (float)WW, idx, w);
#pragma unroll
        for (int j = 0; j < 4; ++j) { s_xo[p][j] = idx[j] * COLQ; s_xw[p][j] = w[j]; }
    }
    __syncthreads();

    const int pw  = t >> 4;          // 0..6 active, 7 idle
    const int chq = t & 15;
    if (pw < PP) {
        const int   xo0 = s_xo[pw][0], xo1 = s_xo[pw][1], xo2 = s_xo[pw][2], xo3 = s_xo[pw][3];
        const float w0 = s_xw[pw][0], w1 = s_xw[pw][1], w2 = s_xw[pw][2], w3 = s_xw[pw][3];
        f32x2 a0[PP] = {};           // channels c0,c0+1
        f32x2 a1[PP] = {};           // channels c0+2,c0+3
        const uint2* p = fmap4 + (size_t)b * (HH * ROWQ) + (size_t)ylo * ROWQ
                       + quarter * NQ + chq;
#pragma unroll 2
        for (int y = 0; y < ny; ++y, p += ROWQ) {
            const uint2 q0 = p[xo0], q1 = p[xo1], q2 = p[xo2], q3 = p[xo3];  // 8B/lane
            // x-reduce, packed over channel pairs: 8 pk_fma (+2 pk_mul)
            f32x2 txy = bfpair(q0.x) * w0;
            f32x2 tzw = bfpair(q0.y) * w0;
            txy = fma2(bfpair(q1.x), w1, txy);
            tzw = fma2(bfpair(q1.y), w1, tzw);
            txy = fma2(bfpair(q2.x), w2, txy);
            tzw = fma2(bfpair(q2.y), w2, tzw);
            txy = fma2(bfpair(q3.x), w3, txy);
            tzw = fma2(bfpair(q3.y), w3, tzw);
#pragma unroll
            for (int ph = 0; ph < PP; ++ph) {        // 14 pk_fma
                const float wy = s_wd[ph][y];        // uniform LDS broadcast
                a0[ph] = fma2(txy, wy, a0[ph]);
                a1[ph] = fma2(tzw, wy, a1[ph]);
            }
        }
        const int c0 = chq * 4;
#pragma unroll
        for (int ph = 0; ph < PP; ++ph) {            // 32 distinct banks x 2 lanes: free
            const int bin = ph * PP + pw;
            sout[(c0 + 0) * NBIN + bin] = a0[ph][0];
            sout[(c0 + 1) * NBIN + bin] = a0[ph][1];
            sout[(c0 + 2) * NBIN + bin] = a1[ph][0];
            sout[(c0 + 3) * NBIN + bin] = a1[ph][1];
        }
    }
    __syncthreads();

    // epilogue: 12544 contiguous bytes per block, nontemporal float4
    f32x4* o4 = (f32x4*)(out + (size_t)k * (CC * NBIN) + (size_t)quarter * (CH * NBIN));
    const f32x4* s4 = (const f32x4*)sout;
    for (int i = t; i < CH * NBIN / 4; i += 128)
        __builtin_nontemporal_store(s4[i], &o4[i]);
}

// --- fallback: direct NCHW f32 (only if ws too small) ---
__global__ __launch_bounds__(256) void roialign_nchw_kernel(const float* __restrict__ fmap,
                                                            const float* __restrict__ rois,
                                                            float* __restrict__ out) {
    __shared__ __align__(16) float sbuf[CC * NBIN];
    const int k = blockIdx.x;
    const int t = threadIdx.x;
    const int   b  = (int)rois[k * 5 + 0];
    const float x1 = rois[k * 5 + 1] * SCALE;
    const float y1 = rois[k * 5 + 2] * SCALE;
    const float x2 = rois[k * 5 + 3] * SCALE;
    const float y2 = rois[k * 5 + 4] * SCALE;
    const float bw = fmaxf(x2 - x1, 1.0f) * (1.0f / PP);
    const float bh = fmaxf(y2 - y1, 1.0f) * (1.0f / PP);
    for (int ph = 0; ph < PP; ++ph) {
        int ys[4]; float wy[4];
        axis_samples(y1, bh, ph, (float)HH, ys, wy);
        for (int pw = 0; pw < PP; ++pw) {
            int xs[4]; float wx[4];
            axis_samples(x1, bw, pw, (float)WW, xs, wx);
            float acc = 0.0f;
#pragma unroll
            for (int i = 0; i < 4; ++i)
#pragma unroll
                for (int j = 0; j < 4; ++j)
                    acc = fmaf(wy[i] * wx[j],
                               fmap[((size_t)(b * CC + t) * HH + ys[i]) * WW + xs[j]], acc);
            sbuf[t * NBIN + ph * PP + pw] = acc * 0.25f;
        }
    }
    __syncthreads();
    float4* o4 = (float4*)(out + (size_t)k * (CC * NBIN));
    const float4* s4 = (const float4*)sbuf;
    for (int i = t; i < (CC * NBIN) / 4; i += 256) o4[i] = s4[i];
}

extern "C" void kernel_launch(void* const* d_in, const int* in_sizes, int n_in,
                              void* d_out, int out_size, void* d_ws, size_t ws_size,
                              hipStream_t stream) {
    const float* input = (const float*)d_in[0];   // [B,C,H,W] f32
    const float* rois  = (const float*)d_in[1];   // [K,5] f32
    float* out = (float*)d_out;                   // [K,C,7,7] f32

    const size_t need = (size_t)BB * HH * WW * CC * sizeof(unsigned short);  // 5.12 MB
    if (ws_size >= need) {
        unsigned short* fmap = (unsigned short*)d_ws;
        xpose_kernel<<<BB * HH * 8, 128, 0, stream>>>(input, fmap);
        roialign_kernel<<<KK * 4, 128, 0, stream>>>((const uint2*)fmap, rois, out);
    } else {
        roialign_nchw_kernel<<<KK, 256, 0, stream>>>(input, rois, out);
    }
}

// Round 14
// 28.790 us; speedup vs baseline: 1.1764x; 1.0120x over previous
//
#include <hip/hip_runtime.h>

#define BB 4
#define CC 256
#define HH 50
#define WW 50
#define KK 1000
#define PP 7
#define NBIN 49              // 7*7
#define SCALE 0.0625f        // 1/16
#define CH 64                // channels per gather block
#define NQ (CH / 4)          // 16 channel-quads
#define ROWQ (WW * CC / 4)   // quad stride of one y row in NHWC = 3200
#define COLQ (CC / 4)        // quad stride of one x step = 64
#define WDS 52               // padded Wd rows (ny <= 50)

typedef float f32x4 __attribute__((ext_vector_type(4)));
typedef float f32x2 __attribute__((ext_vector_type(2)));

__device__ __forceinline__ unsigned short f32_to_bf(float f) {
    union { float f; unsigned int i; } c; c.f = f;
    const unsigned int r = c.i + 0x7FFFu + ((c.i >> 16) & 1u);   // round-nearest-even
    return (unsigned short)(r >> 16);
}
// u = (bf16 a | bf16 b<<16)  ->  {f32(a), f32(b)}
__device__ __forceinline__ f32x2 bfpair(unsigned int u) {
    union { unsigned int i; float f; } a, b;
    a.i = u << 16;
    b.i = u & 0xFFFF0000u;
    f32x2 r; r[0] = a.f; r[1] = b.f;
    return r;
}
__device__ __forceinline__ f32x2 fma2(f32x2 a, float b, f32x2 c) {
    return a * b + c;    // compiler emits v_pk_fma_f32
}

// --- per-axis sample computation, replicating reference boundary handling ---
__device__ __forceinline__ void axis_samples(float start, float bin, int p, float limit,
                                             int idx[4], float w[4]) {
#pragma unroll
    for (int i = 0; i < 2; ++i) {
        float s = (float)(p * 2 + i);
        float c = start + bin * (s + 0.5f) * 0.5f;   // /SR==2 exact as *0.5
        bool valid = (c > -1.0f) && (c < limit);
        c = fmaxf(c, 0.0f);
        float low = floorf(c);
        float high;
        if (low >= limit - 1.0f) { low = limit - 1.0f; c = low; high = low; }
        else high = low + 1.0f;
        float frac = c - low;
        idx[i * 2 + 0] = (int)low;
        idx[i * 2 + 1] = (int)high;
        w[i * 2 + 0] = valid ? (1.0f - frac) : 0.0f;
        w[i * 2 + 1] = valid ? frac : 0.0f;
    }
}

// --- NCHW f32 -> NHWC bf16 transpose: block per (b, y, 32-ch eighth) ---
__global__ __launch_bounds__(128) void xpose_kernel(const float* __restrict__ in,
                                                    unsigned short* __restrict__ out) {
    __shared__ float tile[32 * 51];           // 6528 B, stride-51 pad
    const int bid   = blockIdx.x;
    const int e     = bid & 7;                // 32-channel slice
    const int rem   = bid >> 3;
    const int y     = rem % HH;
    const int b     = rem / HH;
    const int t     = threadIdx.x;
    const int cbase = e * 32;
    for (int i = t; i < 32 * 25; i += 128) {
        const int c = i / 25, x2 = i % 25;
        const float2 v = *(const float2*)(in +
            (((size_t)(b * CC + cbase + c) * HH + y) * WW + 2 * x2));
        tile[c * 51 + 2 * x2]     = v.x;
        tile[c * 51 + 2 * x2 + 1] = v.y;
    }
    __syncthreads();
    unsigned short* ob = out + ((size_t)(b * HH + y) * WW) * CC + cbase;
    for (int j = t; j < WW * 8; j += 128) {
        const int x  = j >> 3;                // 8 channel-quads per x (this eighth)
        const int c0 = (j & 7) * 4;
        ushort4 v;
        v.x = f32_to_bf(tile[(c0 + 0) * 51 + x]);
        v.y = f32_to_bf(tile[(c0 + 1) * 51 + x]);
        v.z = f32_to_bf(tile[(c0 + 2) * 51 + x]);
        v.w = f32_to_bf(tile[(c0 + 3) * 51 + x]);
        *(ushort4*)(ob + (size_t)x * CC + c0) = v;   // keep in L2 for the gather
    }
}

// --- separable gather: block = (ROI, 64-ch quarter); thread = (pw, chq) ---
// XCD-aware decode: each XCD (bid&7) owns ONE channel quarter -> 1.28 MB slice
// is L2-resident on that XCD.
__global__ __launch_bounds__(128) void roialign_kernel(const uint2* __restrict__ fmap4,
                                                       const float* __restrict__ rois,
                                                       float* __restrict__ out) {
    __shared__ __align__(16) float sout[CH * NBIN];   // 12544 B, [c][49]
    __shared__ float s_wd[PP][WDS];                   // collapsed y-weights (x0.25)
    __shared__ int   s_xo[PP][4];                     // x tap offsets (quad units)
    __shared__ float s_xw[PP][4];

    const int bid     = blockIdx.x;
    const int xcd     = bid & 7;               // dispatch round-robin -> XCD id
    const int k       = (bid >> 3) * 2 + (xcd & 1);   // ROI (bijective)
    const int quarter = xcd >> 1;              // channel quarter pinned per XCD pair
    const int t       = threadIdx.x;

    const int   b  = (int)rois[k * 5 + 0];
    const float x1 = rois[k * 5 + 1] * SCALE;
    const float y1 = rois[k * 5 + 2] * SCALE;
    const float x2 = rois[k * 5 + 3] * SCALE;
    const float y2 = rois[k * 5 + 4] * SCALE;
    const float bw = fmaxf(x2 - x1, 1.0f) * (1.0f / PP);
    const float bh = fmaxf(y2 - y1, 1.0f) * (1.0f / PP);

    // y bbox from the monotone extreme samples (s=0 lowest tap, s=13 highest)
    float c0f = fmaxf(y1 + bh * 0.25f, 0.0f);
    float l0 = floorf(c0f);
    if (l0 >= HH - 1.0f) l0 = HH - 1.0f;
    const int ylo = (int)l0;
    float c1f = fmaxf(y1 + bh * 6.75f, 0.0f);
    float l1 = floorf(c1f);
    float h1 = (l1 >= HH - 1.0f) ? (HH - 1.0f) : (l1 + 1.0f);
    const int ny = (int)h1 - ylo + 1;    // <= 50 always (indices clamped to [0,49])

    // single-sync table build: thread t<7 owns Wd row t (zero just [0,ny) + scatter)
    if (t < PP) {
        for (int y = 0; y < ny; ++y) s_wd[t][y] = 0.0f;
        int idx[4]; float w[4];
        axis_samples(y1, bh, t, (float)HH, idx, w);
#pragma unroll
        for (int j = 0; j < 4; ++j) s_wd[t][idx[j] - ylo] += 0.25f * w[j];
    } else if (t >= 64 && t < 64 + PP) {          // x tables (other wave, parallel)
        const int p = t - 64;
        int idx[4]; float w[4];
        axis_samples(x1, bw, p, (float)WW, idx, w);
#pragma unroll
        for (int j = 0; j < 4; ++j) { s_xo[p][j] = idx[j] * COLQ; s_xw[p][j] = w[j]; }
    }
    __syncthreads();

    const int pw  = t >> 4;          // 0..6 active, 7 idle
    const int chq = t & 15;
    if (pw < PP) {
        const int   xo0 = s_xo[pw][0], xo1 = s_xo[pw][1], xo2 = s_xo[pw][2], xo3 = s_xo[pw][3];
        const float w0 = s_xw[pw][0], w1 = s_xw[pw][1], w2 = s_xw[pw][2], w3 = s_xw[pw][3];
        f32x2 a0[PP] = {};           // channels c0,c0+1
        f32x2 a1[PP] = {};           // channels c0+2,c0+3
        const uint2* p = fmap4 + (size_t)b * (HH * ROWQ) + (size_t)ylo * ROWQ
                       + quarter * NQ + chq;
#pragma unroll 4
        for (int y = 0; y < ny; ++y, p += ROWQ) {
            const uint2 q0 = p[xo0], q1 = p[xo1], q2 = p[xo2], q3 = p[xo3];  // 8B/lane
            f32x2 txy = bfpair(q0.x) * w0;
            f32x2 tzw = bfpair(q0.y) * w0;
            txy = fma2(bfpair(q1.x), w1, txy);
            tzw = fma2(bfpair(q1.y), w1, tzw);
            txy = fma2(bfpair(q2.x), w2, txy);
            tzw = fma2(bfpair(q2.y), w2, tzw);
            txy = fma2(bfpair(q3.x), w3, txy);
            tzw = fma2(bfpair(q3.y), w3, tzw);
#pragma unroll
            for (int ph = 0; ph < PP; ++ph) {        // 14 pk_fma
                const float wy = s_wd[ph][y];        // uniform LDS broadcast
                a0[ph] = fma2(txy, wy, a0[ph]);
                a1[ph] = fma2(tzw, wy, a1[ph]);
            }
        }
        const int c0 = chq * 4;
#pragma unroll
        for (int ph = 0; ph < PP; ++ph) {            // 32 distinct banks x 2 lanes: free
            const int bin = ph * PP + pw;
            sout[(c0 + 0) * NBIN + bin] = a0[ph][0];
            sout[(c0 + 1) * NBIN + bin] = a0[ph][1];
            sout[(c0 + 2) * NBIN + bin] = a1[ph][0];
            sout[(c0 + 3) * NBIN + bin] = a1[ph][1];
        }
    }
    __syncthreads();

    // epilogue: 12544 contiguous bytes per block, nontemporal float4
    f32x4* o4 = (f32x4*)(out + (size_t)k * (CC * NBIN) + (size_t)quarter * (CH * NBIN));
    const f32x4* s4 = (const f32x4*)sout;
    for (int i = t; i < CH * NBIN / 4; i += 128)
        __builtin_nontemporal_store(s4[i], &o4[i]);
}

// --- fallback: direct NCHW f32 (only if ws too small) ---
__global__ __launch_bounds__(256) void roialign_nchw_kernel(const float* __restrict__ fmap,
                                                            const float* __restrict__ rois,
                                                            float* __restrict__ out) {
    __shared__ __align__(16) float sbuf[CC * NBIN];
    const int k = blockIdx.x;
    const int t = threadIdx.x;
    const int   b  = (int)rois[k * 5 + 0];
    const float x1 = rois[k * 5 + 1] * SCALE;
    const float y1 = rois[k * 5 + 2] * SCALE;
    const float x2 = rois[k * 5 + 3] * SCALE;
    const float y2 = rois[k * 5 + 4] * SCALE;
    const float bw = fmaxf(x2 - x1, 1.0f) * (1.0f / PP);
    const float bh = fmaxf(y2 - y1, 1.0f) * (1.0f / PP);
    for (int ph = 0; ph < PP; ++ph) {
        int ys[4]; float wy[4];
        axis_samples(y1, bh, ph, (float)HH, ys, wy);
        for (int pw = 0; pw < PP; ++pw) {
            int xs[4]; float wx[4];
            axis_samples(x1, bw, pw, (float)WW, xs, wx);
            float acc = 0.0f;
#pragma unroll
            for (int i = 0; i < 4; ++i)
#pragma unroll
                for (int j = 0; j < 4; ++j)
                    acc = fmaf(wy[i] * wx[j],
                               fmap[((size_t)(b * CC + t) * HH + ys[i]) * WW + xs[j]], acc);
            sbuf[t * NBIN + ph * PP + pw] = acc * 0.25f;
        }
    }
    __syncthreads();
    float4* o4 = (float4*)(out + (size_t)k * (CC * NBIN));
    const float4* s4 = (const float4*)sbuf;
    for (int i = t; i < (CC * NBIN) / 4; i += 256) o4[i] = s4[i];
}

extern "C" void kernel_launch(void* const* d_in, const int* in_sizes, int n_in,
                              void* d_out, int out_size, void* d_ws, size_t ws_size,
                              hipStream_t stream) {
    const float* input = (const float*)d_in[0];   // [B,C,H,W] f32
    const float* rois  = (const float*)d_in[1];   // [K,5] f32
    float* out = (float*)d_out;                   // [K,C,7,7] f32

    const size_t need = (size_t)BB * HH * WW * CC * sizeof(unsigned short);  // 5.12 MB
    if (ws_size >= need) {
        unsigned short* fmap = (unsigned short*)d_ws;
        xpose_kernel<<<BB * HH * 8, 128, 0, stream>>>(input, fmap);
        roialign_kernel<<<KK * 4, 128, 0, stream>>>((const uint2*)fmap, rois, out);
    } else {
        roialign_nchw_kernel<<<KK, 256, 0, stream>>>(input, rois, out);
    }
}

// Round 15
// 26.583 us; speedup vs baseline: 1.2741x; 1.0830x over previous
//
#include <hip/hip_runtime.h>

#define BB 4
#define CC 256
#define HH 50
#define WW 50
#define KK 1000
#define PP 7
#define NBIN 49              // 7*7
#define SCALE 0.0625f        // 1/16
#define CH 32                // channels per gather block (one 64-lane wave)
#define NQ (CH / 4)          // 8 channel-quads
#define ROWQ (WW * CC / 4)   // quad stride of one y row in NHWC = 3200
#define COLQ (CC / 4)        // quad stride of one x step = 64
#define WDS 52               // padded Wd rows (ny <= 50)

typedef float f32x4 __attribute__((ext_vector_type(4)));
typedef float f32x2 __attribute__((ext_vector_type(2)));

__device__ __forceinline__ unsigned short f32_to_bf(float f) {
    union { float f; unsigned int i; } c; c.f = f;
    const unsigned int r = c.i + 0x7FFFu + ((c.i >> 16) & 1u);   // round-nearest-even
    return (unsigned short)(r >> 16);
}
// u = (bf16 a | bf16 b<<16)  ->  {f32(a), f32(b)}
__device__ __forceinline__ f32x2 bfpair(unsigned int u) {
    union { unsigned int i; float f; } a, b;
    a.i = u << 16;
    b.i = u & 0xFFFF0000u;
    f32x2 r; r[0] = a.f; r[1] = b.f;
    return r;
}
__device__ __forceinline__ f32x2 fma2(f32x2 a, float b, f32x2 c) {
    return a * b + c;    // compiler emits v_pk_fma_f32
}

// --- per-axis sample computation, replicating reference boundary handling ---
__device__ __forceinline__ void axis_samples(float start, float bin, int p, float limit,
                                             int idx[4], float w[4]) {
#pragma unroll
    for (int i = 0; i < 2; ++i) {
        float s = (float)(p * 2 + i);
        float c = start + bin * (s + 0.5f) * 0.5f;   // /SR==2 exact as *0.5
        bool valid = (c > -1.0f) && (c < limit);
        c = fmaxf(c, 0.0f);
        float low = floorf(c);
        float high;
        if (low >= limit - 1.0f) { low = limit - 1.0f; c = low; high = low; }
        else high = low + 1.0f;
        float frac = c - low;
        idx[i * 2 + 0] = (int)low;
        idx[i * 2 + 1] = (int)high;
        w[i * 2 + 0] = valid ? (1.0f - frac) : 0.0f;
        w[i * 2 + 1] = valid ? frac : 0.0f;
    }
}

// --- NCHW f32 -> NHWC bf16 transpose: block per (b, y, 32-ch eighth) ---
__global__ __launch_bounds__(128) void xpose_kernel(const float* __restrict__ in,
                                                    unsigned short* __restrict__ out) {
    __shared__ float tile[32 * 51];           // 6528 B, stride-51 pad
    const int bid   = blockIdx.x;
    const int e     = bid & 7;                // 32-channel slice
    const int rem   = bid >> 3;
    const int y     = rem % HH;
    const int b     = rem / HH;
    const int t     = threadIdx.x;
    const int cbase = e * 32;
    for (int i = t; i < 32 * 25; i += 128) {
        const int c = i / 25, x2 = i % 25;
        const float2 v = *(const float2*)(in +
            (((size_t)(b * CC + cbase + c) * HH + y) * WW + 2 * x2));
        tile[c * 51 + 2 * x2]     = v.x;
        tile[c * 51 + 2 * x2 + 1] = v.y;
    }
    __syncthreads();
    unsigned short* ob = out + ((size_t)(b * HH + y) * WW) * CC + cbase;
    for (int j = t; j < WW * 8; j += 128) {
        const int x  = j >> 3;                // 8 channel-quads per x (this eighth)
        const int c0 = (j & 7) * 4;
        ushort4 v;
        v.x = f32_to_bf(tile[(c0 + 0) * 51 + x]);
        v.y = f32_to_bf(tile[(c0 + 1) * 51 + x]);
        v.z = f32_to_bf(tile[(c0 + 2) * 51 + x]);
        v.w = f32_to_bf(tile[(c0 + 3) * 51 + x]);
        *(ushort4*)(ob + (size_t)x * CC + c0) = v;   // keep in L2 for the gather
    }
}

// --- separable gather: ONE WAVE per (ROI, 32-ch eighth); 8000 blocks ---
// Full-grid residency: 8000 waves / 256 CU = 31.25 <= 32 waves/CU.
// e = bid&7 pins each XCD to one 0.64 MB channel slice (L2-resident).
__global__ __launch_bounds__(64, 8) void roialign_kernel(const uint2* __restrict__ fmap4,
                                                         const float* __restrict__ rois,
                                                         float* __restrict__ out) {
    __shared__ __align__(16) float sout[CH * NBIN];   // 6272 B, [c][49]
    __shared__ float s_wd[PP][WDS];                   // collapsed y-weights (x0.25)
    __shared__ int   s_xo[PP][4];                     // x tap offsets (quad units)
    __shared__ float s_xw[PP][4];

    const int bid = blockIdx.x;
    const int e   = bid & 7;             // channel eighth == XCD slot
    const int k   = bid >> 3;            // ROI
    const int t   = threadIdx.x;

    const int   b  = (int)rois[k * 5 + 0];
    const float x1 = rois[k * 5 + 1] * SCALE;
    const float y1 = rois[k * 5 + 2] * SCALE;
    const float x2 = rois[k * 5 + 3] * SCALE;
    const float y2 = rois[k * 5 + 4] * SCALE;
    const float bw = fmaxf(x2 - x1, 1.0f) * (1.0f / PP);
    const float bh = fmaxf(y2 - y1, 1.0f) * (1.0f / PP);

    // y bbox from the monotone extreme samples (s=0 lowest tap, s=13 highest)
    float c0f = fmaxf(y1 + bh * 0.25f, 0.0f);
    float l0 = floorf(c0f);
    if (l0 >= HH - 1.0f) l0 = HH - 1.0f;
    const int ylo = (int)l0;
    float c1f = fmaxf(y1 + bh * 6.75f, 0.0f);
    float l1 = floorf(c1f);
    float h1 = (l1 >= HH - 1.0f) ? (HH - 1.0f) : (l1 + 1.0f);
    const int ny = (int)h1 - ylo + 1;    // <= 50 always (indices clamped to [0,49])

    // table build inside one wave: lanes 0-6 own Wd rows, lanes 32-38 own x tables
    if (t < PP) {
        for (int y = 0; y < ny; ++y) s_wd[t][y] = 0.0f;
        int idx[4]; float w[4];
        axis_samples(y1, bh, t, (float)HH, idx, w);
#pragma unroll
        for (int j = 0; j < 4; ++j) s_wd[t][idx[j] - ylo] += 0.25f * w[j];
    } else if (t >= 32 && t < 32 + PP) {
        const int p = t - 32;
        int idx[4]; float w[4];
        axis_samples(x1, bw, p, (float)WW, idx, w);
#pragma unroll
        for (int j = 0; j < 4; ++j) { s_xo[p][j] = idx[j] * COLQ; s_xw[p][j] = w[j]; }
    }
    __syncthreads();   // one wave: compiles to s_waitcnt, no real barrier cost

    const int pw  = t >> 3;          // 0..6 active, 7 idle
    const int chq = t & 7;
    if (pw < PP) {
        const int   xo0 = s_xo[pw][0], xo1 = s_xo[pw][1], xo2 = s_xo[pw][2], xo3 = s_xo[pw][3];
        const float w0 = s_xw[pw][0], w1 = s_xw[pw][1], w2 = s_xw[pw][2], w3 = s_xw[pw][3];
        f32x2 a0[PP] = {};           // channels c0,c0+1
        f32x2 a1[PP] = {};           // channels c0+2,c0+3
        const uint2* p = fmap4 + (size_t)b * (HH * ROWQ) + (size_t)ylo * ROWQ
                       + e * NQ + chq;
#pragma unroll 2
        for (int y = 0; y < ny; ++y, p += ROWQ) {
            const uint2 q0 = p[xo0], q1 = p[xo1], q2 = p[xo2], q3 = p[xo3];  // 8B/lane
            f32x2 txy = bfpair(q0.x) * w0;
            f32x2 tzw = bfpair(q0.y) * w0;
            txy = fma2(bfpair(q1.x), w1, txy);
            tzw = fma2(bfpair(q1.y), w1, tzw);
            txy = fma2(bfpair(q2.x), w2, txy);
            tzw = fma2(bfpair(q2.y), w2, tzw);
            txy = fma2(bfpair(q3.x), w3, txy);
            tzw = fma2(bfpair(q3.y), w3, tzw);
#pragma unroll
            for (int ph = 0; ph < PP; ++ph) {        // 14 pk_fma
                const float wy = s_wd[ph][y];        // uniform LDS broadcast
                a0[ph] = fma2(txy, wy, a0[ph]);
                a1[ph] = fma2(tzw, wy, a1[ph]);
            }
        }
        const int c0 = chq * 4;
#pragma unroll
        for (int ph = 0; ph < PP; ++ph) {            // <=2 lanes/bank: free
            const int bin = ph * PP + pw;
            sout[(c0 + 0) * NBIN + bin] = a0[ph][0];
            sout[(c0 + 1) * NBIN + bin] = a0[ph][1];
            sout[(c0 + 2) * NBIN + bin] = a1[ph][0];
            sout[(c0 + 3) * NBIN + bin] = a1[ph][1];
        }
    }
    __syncthreads();

    // epilogue: 6272 contiguous bytes per block, nontemporal float4
    f32x4* o4 = (f32x4*)(out + (size_t)k * (CC * NBIN) + (size_t)e * (CH * NBIN));
    const f32x4* s4 = (const f32x4*)sout;
    for (int i = t; i < CH * NBIN / 4; i += 64)
        __builtin_nontemporal_store(s4[i], &o4[i]);
}

// --- fallback: direct NCHW f32 (only if ws too small) ---
__global__ __launch_bounds__(256) void roialign_nchw_kernel(const float* __restrict__ fmap,
                                                            const float* __restrict__ rois,
                                                            float* __restrict__ out) {
    __shared__ __align__(16) float sbuf[CC * NBIN];
    const int k = blockIdx.x;
    const int t = threadIdx.x;
    const int   b  = (int)rois[k * 5 + 0];
    const float x1 = rois[k * 5 + 1] * SCALE;
    const float y1 = rois[k * 5 + 2] * SCALE;
    const float x2 = rois[k * 5 + 3] * SCALE;
    const float y2 = rois[k * 5 + 4] * SCALE;
    const float bw = fmaxf(x2 - x1, 1.0f) * (1.0f / PP);
    const float bh = fmaxf(y2 - y1, 1.0f) * (1.0f / PP);
    for (int ph = 0; ph < PP; ++ph) {
        int ys[4]; float wy[4];
        axis_samples(y1, bh, ph, (float)HH, ys, wy);
        for (int pw = 0; pw < PP; ++pw) {
            int xs[4]; float wx[4];
            axis_samples(x1, bw, pw, (float)WW, xs, wx);
            float acc = 0.0f;
#pragma unroll
            for (int i = 0; i < 4; ++i)
#pragma unroll
                for (int j = 0; j < 4; ++j)
                    acc = fmaf(wy[i] * wx[j],
                               fmap[((size_t)(b * CC + t) * HH + ys[i]) * WW + xs[j]], acc);
            sbuf[t * NBIN + ph * PP + pw] = acc * 0.25f;
        }
    }
    __syncthreads();
    float4* o4 = (float4*)(out + (size_t)k * (CC * NBIN));
    const float4* s4 = (const float4*)sbuf;
    for (int i = t; i < (CC * NBIN) / 4; i += 256) o4[i] = s4[i];
}

extern "C" void kernel_launch(void* const* d_in, const int* in_sizes, int n_in,
                              void* d_out, int out_size, void* d_ws, size_t ws_size,
                              hipStream_t stream) {
    const float* input = (const float*)d_in[0];   // [B,C,H,W] f32
    const float* rois  = (const float*)d_in[1];   // [K,5] f32
    float* out = (float*)d_out;                   // [K,C,7,7] f32

    const size_t need = (size_t)BB * HH * WW * CC * sizeof(unsigned short);  // 5.12 MB
    if (ws_size >= need) {
        unsigned short* fmap = (unsigned short*)d_ws;
        xpose_kernel<<<BB * HH * 8, 128, 0, stream>>>(input, fmap);
        roialign_kernel<<<KK * 8, 64, 0, stream>>>((const uint2*)fmap, rois, out);
    } else {
        roialign_nchw_kernel<<<KK, 256, 0, stream>>>(input, rois, out);
    }
}